// Round 5
// baseline (340.665 us; speedup 1.0000x reference)
//
#include <hip/hip_runtime.h>
#include <math.h>

#define LTOK 2304
#define CDIM 768
#define NHEAD 12
#define HDIM 64
#define HS 48

static constexpr float ATT_SCALE = 0.125f;  // 64^-0.5

typedef short s16x8 __attribute__((ext_vector_type(8)));   // 8 bf16 bits (4 VGPRs)
typedef float f32x4 __attribute__((ext_vector_type(4)));

__device__ __forceinline__ unsigned short f2b(float f) {
  __bf16 b = (__bf16)f;   // RNE
  return __builtin_bit_cast(unsigned short, b);
}
__device__ __forceinline__ float b2f(unsigned short u) {
  unsigned int x = ((unsigned int)u) << 16;
  return __builtin_bit_cast(float, x);
}

__device__ __forceinline__ void gld_lds16(void* lds, const void* g) {
  __builtin_amdgcn_global_load_lds(
      (const __attribute__((address_space(1))) unsigned int*)g,
      (__attribute__((address_space(3))) unsigned int*)lds, 16, 0, 0);
}

// ---------------- fp32 -> bf16 convert (n % 8 == 0) ----------------
__global__ __launch_bounds__(256) void f2b_kernel(const float* __restrict__ in,
                                                  unsigned short* __restrict__ out, int n) {
  const int i = (blockIdx.x * 256 + threadIdx.x) * 8;
  if (i + 8 > n) return;
  float4 v0 = *(const float4*)(in + i);
  float4 v1 = *(const float4*)(in + i + 4);
  alignas(16) unsigned short o[8] = {f2b(v0.x), f2b(v0.y), f2b(v0.z), f2b(v0.w),
                                     f2b(v1.x), f2b(v1.y), f2b(v1.z), f2b(v1.w)};
  *(uint4*)(out + i) = *(const uint4*)o;
}

// ---------------- LayerNorm: fp32 in, bf16 out ----------------
__global__ __launch_bounds__(256) void ln_kernel(const float* __restrict__ x,
                                                 const float* __restrict__ w,
                                                 const float* __restrict__ b,
                                                 unsigned short* __restrict__ out) {
  const int row = blockIdx.x;
  const int t = threadIdx.x;
  const float* xr = x + (size_t)row * CDIM;
  float v0 = xr[t], v1 = xr[t + 256], v2 = xr[t + 512];
  float s = v0 + v1 + v2;
  float ss = v0 * v0 + v1 * v1 + v2 * v2;
#pragma unroll
  for (int off = 32; off > 0; off >>= 1) {
    s += __shfl_down(s, off, 64);
    ss += __shfl_down(ss, off, 64);
  }
  __shared__ float rs[4], rss[4];
  if ((t & 63) == 0) { rs[t >> 6] = s; rss[t >> 6] = ss; }
  __syncthreads();
  float S = rs[0] + rs[1] + rs[2] + rs[3];
  float SS = rss[0] + rss[1] + rss[2] + rss[3];
  const float inv_c = 1.0f / (float)CDIM;
  float mu = S * inv_c;
  float var = SS * inv_c - mu * mu;
  float inv = rsqrtf(var + 1e-5f);
  unsigned short* orow = out + (size_t)row * CDIM;
  orow[t]       = f2b((v0 - mu) * inv * w[t]       + b[t]);
  orow[t + 256] = f2b((v1 - mu) * inv * w[t + 256] + b[t + 256]);
  orow[t + 512] = f2b((v2 - mu) * inv * w[t + 512] + b[t + 512]);
}

// ---------------- bf16 MFMA GEMM (m97 structure) ----------------
template <bool GELU, bool RES, bool OUTBF>
__global__ __launch_bounds__(256) void mfma_gemm(const unsigned short* __restrict__ A,
                                                 const unsigned short* __restrict__ B,
                                                 const float* __restrict__ bias,
                                                 const float* __restrict__ res,
                                                 void* __restrict__ Cout,
                                                 int M, int N, int K) {
  __shared__ unsigned short As[128 * 32];
  __shared__ unsigned short Bs[128 * 32];
  const int t = threadIdx.x;
  const int lane = t & 63;
  const int w = t >> 6;
  const int wm = w >> 1, wn = w & 1;
  const int bm = blockIdx.y * 128, bn = blockIdx.x * 128;

  f32x4 acc[4][4] = {};

  const int c0 = 2 * w, c1 = 2 * w + 1;
  const int srow = lane >> 2;
  const int skof = (lane & 3) * 8;
  const unsigned short* Abase = A + (size_t)bm * K + skof;
  const unsigned short* Bbase = B + (size_t)bn * K + skof;
  const int lr = lane & 15, lk = (lane >> 4) * 8, lg = lane >> 4;

  for (int k0 = 0; k0 < K; k0 += 32) {
    gld_lds16(As + c0 * 512, Abase + (size_t)(c0 * 16 + srow) * K + k0);
    gld_lds16(As + c1 * 512, Abase + (size_t)(c1 * 16 + srow) * K + k0);
    gld_lds16(Bs + c0 * 512, Bbase + (size_t)(c0 * 16 + srow) * K + k0);
    gld_lds16(Bs + c1 * 512, Bbase + (size_t)(c1 * 16 + srow) * K + k0);
    __syncthreads();
    s16x8 a[4], b[4];
#pragma unroll
    for (int m = 0; m < 4; ++m)
      a[m] = *(const s16x8*)&As[(wm * 64 + m * 16 + lr) * 32 + lk];
#pragma unroll
    for (int n = 0; n < 4; ++n)
      b[n] = *(const s16x8*)&Bs[(wn * 64 + n * 16 + lr) * 32 + lk];
#pragma unroll
    for (int m = 0; m < 4; ++m)
#pragma unroll
      for (int n = 0; n < 4; ++n)
        acc[m][n] = __builtin_amdgcn_mfma_f32_16x16x32_bf16(a[m], b[n], acc[m][n], 0, 0, 0);
    __syncthreads();
  }

#pragma unroll
  for (int n = 0; n < 4; ++n) {
    const int col = bn + wn * 64 + n * 16 + lr;
    const float bc = bias[col];
#pragma unroll
    for (int m = 0; m < 4; ++m) {
#pragma unroll
      for (int j = 0; j < 4; ++j) {
        const int row = bm + wm * 64 + m * 16 + lg * 4 + j;
        float v = acc[m][n][j] + bc;
        if (GELU) v = 0.5f * v * (1.0f + erff(v * 0.70710678118654752f));
        if (RES) v += res[(size_t)row * N + col];
        if (OUTBF) ((unsigned short*)Cout)[(size_t)row * N + col] = f2b(v);
        else       ((float*)Cout)[(size_t)row * N + col] = v;
      }
    }
  }
}

// ---------------- RoPE cos/sin tables: [L][32] ----------------
__global__ __launch_bounds__(256) void rope_cs_kernel(float* __restrict__ cs,
                                                      float* __restrict__ sn) {
  const int idx = blockIdx.x * 256 + threadIdx.x;  // < 2304*32
  const int l = idx >> 5;
  const int i = idx & 31;
  const int j = i & 15;
  const float f = __expf(-(float)j * 0.57564627324851142f);
  const float coord = (i < 16) ? (float)(l % HS) : (float)(l / HS);
  const float ang = coord * f;
  cs[idx] = cosf(ang);
  sn[idx] = sinf(ang);
}

// ---------------- prep: fp32 qkv -> Qb,Kb [NH][L][64] (RoPE) + Vb [NH][64][L] -------
// grid (36, 12), 256 threads
__global__ __launch_bounds__(256) void prep_kernel(const float* __restrict__ qkv,
                                                   const float* __restrict__ cs,
                                                   const float* __restrict__ sn,
                                                   unsigned short* __restrict__ Qb,
                                                   unsigned short* __restrict__ Kb,
                                                   unsigned short* __restrict__ Vb) {
  __shared__ unsigned short Vs[64 * 72];
  const int t = threadIdx.x;
  const int l0 = blockIdx.x * 64, n = blockIdx.y;
  const int r = t >> 2, c = t & 3;
  const int l = l0 + r;
  const float* base = qkv + (size_t)l * (3 * CDIM) + n * HDIM + c * 16;
#pragma unroll
  for (int pq = 0; pq < 2; ++pq) {
    const float* src = base + pq * CDIM;
    alignas(16) unsigned short o[16];
#pragma unroll
    for (int i = 0; i < 4; ++i) {
      float4 v = *(const float4*)(src + i * 4);
      const int pr = c * 8 + i * 2;
      const float c0 = cs[l * 32 + pr],     s0 = sn[l * 32 + pr];
      const float c1 = cs[l * 32 + pr + 1], s1 = sn[l * 32 + pr + 1];
      o[i * 4 + 0] = f2b(v.x * c0 - v.y * s0);
      o[i * 4 + 1] = f2b(v.x * s0 + v.y * c0);
      o[i * 4 + 2] = f2b(v.z * c1 - v.w * s1);
      o[i * 4 + 3] = f2b(v.z * s1 + v.w * c1);
    }
    unsigned short* dst = (pq ? Kb : Qb) + ((size_t)n * LTOK + l) * HDIM + c * 16;
    *(uint4*)dst = *(const uint4*)o;
    *(uint4*)(dst + 8) = *(const uint4*)(o + 8);
  }
  // V transpose via LDS (coalesced in and out)
  {
    const float* vsrc = base + 2 * CDIM;
    alignas(16) unsigned short vo[16];
#pragma unroll
    for (int i = 0; i < 4; ++i) {
      float4 v = *(const float4*)(vsrc + i * 4);
      vo[i * 4 + 0] = f2b(v.x); vo[i * 4 + 1] = f2b(v.y);
      vo[i * 4 + 2] = f2b(v.z); vo[i * 4 + 3] = f2b(v.w);
    }
    *(uint4*)&Vs[r * 72 + c * 16] = *(const uint4*)vo;
    *(uint4*)&Vs[r * 72 + c * 16 + 8] = *(const uint4*)(vo + 8);
  }
  __syncthreads();
  {
    const int d = t >> 2, kc = (t & 3) * 16;
    alignas(16) unsigned short o[16];
#pragma unroll
    for (int i = 0; i < 16; ++i) o[i] = Vs[(kc + i) * 72 + d];
    unsigned short* dst = Vb + ((size_t)n * HDIM + d) * LTOK + l0 + kc;
    *(uint4*)dst = *(const uint4*)o;
    *(uint4*)(dst + 8) = *(const uint4*)(o + 8);
  }
}

// ---------------- MFMA flash attention, KVB=48, split-KV=2 ----------------
// grid (36, 12, 2), 256 threads = 4 waves x 16 q-rows
__global__ __launch_bounds__(256) void attn_mfma(const unsigned short* __restrict__ Qb,
                                                 const unsigned short* __restrict__ Kb,
                                                 const unsigned short* __restrict__ Vb,
                                                 const float* __restrict__ relh,
                                                 const float* __restrict__ relw,
                                                 float* __restrict__ Opart,
                                                 float* __restrict__ ml) {
  __shared__ unsigned short K_lds[48 * 64];        // [key][d], 128B rows, chunk-XOR swizzled
  __shared__ unsigned short Vt_lds[64 * 48 + 16];  // [d][key], 96B rows + zero tail
  __shared__ unsigned short Q_s[64 * 72];          // padded rows
  __shared__ float bh_t[24][64];                   // [kt_local][q]
  __shared__ unsigned short P_lds[4][16 * 72];     // per-wave [q][key(64)], stride 72

  const int t = threadIdx.x;
  const int lane = t & 63, w = t >> 6;
  const int p = lane & 15, g = lane >> 4;
  const int l0 = blockIdx.x * 64, n = blockIdx.y, half = blockIdx.z;
  const int kt0 = half * 24;

  // stage Q tile into padded Q_s
  {
    const int r = t >> 2, c = t & 3;
    const unsigned short* src = Qb + ((size_t)n * LTOK + l0 + r) * HDIM + c * 16;
    uint4 v0 = *(const uint4*)src;
    uint4 v1 = *(const uint4*)(src + 8);
    *(uint4*)&Q_s[r * 72 + c * 16] = v0;
    *(uint4*)&Q_s[r * 72 + c * 16 + 8] = v1;
  }
  if (t < 16) Vt_lds[64 * 48 + t] = 0;
  __syncthreads();

  // Q B-frags (lane's q-row = w*16+p)
  const s16x8 qf0 = *(const s16x8*)&Q_s[(w * 16 + p) * 72 + g * 8];
  const s16x8 qf1 = *(const s16x8*)&Q_s[(w * 16 + p) * 72 + 32 + g * 8];

  // bh_t[kt_local][r]: r = lane, kt_local = w + 4i (6 per wave)
  const int qh_lane = (l0 + lane) / 48;
#pragma unroll
  for (int i = 0; i < 6; ++i) {
    const int ktl = w + 4 * i;
    const float* rrow = relh + (size_t)(qh_lane - (kt0 + ktl) + 47) * HDIM;
    float acc = 0.f;
#pragma unroll
    for (int c8 = 0; c8 < 8; ++c8) {
      s16x8 qv = *(const s16x8*)&Q_s[lane * 72 + c8 * 8];
      float4 ra = *(const float4*)&rrow[c8 * 8];
      float4 rb = *(const float4*)&rrow[c8 * 8 + 4];
      acc += b2f((unsigned short)qv[0]) * ra.x + b2f((unsigned short)qv[1]) * ra.y +
             b2f((unsigned short)qv[2]) * ra.z + b2f((unsigned short)qv[3]) * ra.w +
             b2f((unsigned short)qv[4]) * rb.x + b2f((unsigned short)qv[5]) * rb.y +
             b2f((unsigned short)qv[6]) * rb.z + b2f((unsigned short)qv[7]) * rb.w;
    }
    bh_t[ktl][lane] = acc;
  }

  // bwreg[mb*4+jj] = bw for key j = 16mb + 4g + jj (tile-local, tile-independent)
  float bwreg[12];
  {
    const int qrow = w * 16 + p;
    const int qw_lane = (l0 + qrow) % 48;
#pragma unroll
    for (int mb = 0; mb < 3; ++mb)
#pragma unroll
      for (int jj = 0; jj < 4; ++jj) {
        const int j = 16 * mb + 4 * g + jj;
        const float* rrow = relw + (size_t)(qw_lane - j + 47) * HDIM;
        float acc = 0.f;
#pragma unroll
        for (int c8 = 0; c8 < 8; ++c8) {
          s16x8 qv = *(const s16x8*)&Q_s[qrow * 72 + c8 * 8];
          float4 ra = *(const float4*)&rrow[c8 * 8];
          float4 rb = *(const float4*)&rrow[c8 * 8 + 4];
          acc += b2f((unsigned short)qv[0]) * ra.x + b2f((unsigned short)qv[1]) * ra.y +
                 b2f((unsigned short)qv[2]) * ra.z + b2f((unsigned short)qv[3]) * ra.w +
                 b2f((unsigned short)qv[4]) * rb.x + b2f((unsigned short)qv[5]) * rb.y +
                 b2f((unsigned short)qv[6]) * rb.z + b2f((unsigned short)qv[7]) * rb.w;
        }
        bwreg[mb * 4 + jj] = acc;
      }
  }

  float m = -3e38f, lsum = 0.f;
  f32x4 accO[4] = {};
  const int sw0 = g ^ (p & 7);        // swizzled d-chunk for k=0..31
  const int sw1 = (g + 4) ^ (p & 7);  // k=32..63

  for (int ktl = 0; ktl < 24; ++ktl) {
    const int kt = kt0 + ktl;
    // --- stage K (6 x 1KB chunks; linear LDS dest, XOR-swizzled global source) ---
    {
      const int rowb = lane >> 3;
      const int srcc = (lane & 7) ^ rowb;
      gld_lds16(K_lds + w * 512,
                Kb + ((size_t)n * LTOK + kt * 48 + w * 8 + rowb) * HDIM + srcc * 8);
      if (w < 2) {
        const int c = 4 + w;
        gld_lds16(K_lds + c * 512,
                  Kb + ((size_t)n * LTOK + kt * 48 + c * 8 + rowb) * HDIM + srcc * 8);
      }
      // --- stage Vt (6 x 1KB chunks, 16B/lane; 96B rows, 96%16==0 so spans stay in-row) ---
      {
        const int Bb = w * 1024 + lane * 16;
        const int vr = Bb / 96, vc = (Bb % 96) >> 1;
        gld_lds16(Vt_lds + w * 512,
                  Vb + ((size_t)n * HDIM + vr) * LTOK + kt * 48 + vc);
      }
      if (w >= 2) {
        const int c = 2 + w;  // chunks 4,5
        const int Bb = c * 1024 + lane * 16;
        const int vr = Bb / 96, vc = (Bb % 96) >> 1;
        gld_lds16(Vt_lds + c * 512,
                  Vb + ((size_t)n * HDIM + vr) * LTOK + kt * 48 + vc);
      }
    }
    __syncthreads();

    // --- S^T = K · Q^T : D[key][q], col=lane&15=q, row=4g+jj=key-in-16 ---
    f32x4 st[3] = {};
#pragma unroll
    for (int mb = 0; mb < 3; ++mb) {
      const int krow = (16 * mb + p) * 64;
      s16x8 kf0 = *(const s16x8*)&K_lds[krow + sw0 * 8];
      s16x8 kf1 = *(const s16x8*)&K_lds[krow + sw1 * 8];
      st[mb] = __builtin_amdgcn_mfma_f32_16x16x32_bf16(kf0, qf0, st[mb], 0, 0, 0);
      st[mb] = __builtin_amdgcn_mfma_f32_16x16x32_bf16(kf1, qf1, st[mb], 0, 0, 0);
    }

    // --- bias + online softmax (per lane: q-row = w*16+p, 12 keys) ---
    const float bhv = bh_t[ktl][w * 16 + p];
    float sv[12];
#pragma unroll
    for (int mb = 0; mb < 3; ++mb)
#pragma unroll
      for (int jj = 0; jj < 4; ++jj)
        sv[mb * 4 + jj] = st[mb][jj] * ATT_SCALE + bhv + bwreg[mb * 4 + jj];
    float tm = sv[0];
#pragma unroll
    for (int i = 1; i < 12; ++i) tm = fmaxf(tm, sv[i]);
    tm = fmaxf(tm, __shfl_xor(tm, 16, 64));
    tm = fmaxf(tm, __shfl_xor(tm, 32, 64));
    const float mn = fmaxf(m, tm);
    const float alpha = __expf(m - mn);
    m = mn;
    float pv[12], ps = 0.f;
#pragma unroll
    for (int i = 0; i < 12; ++i) { pv[i] = __expf(sv[i] - mn); ps += pv[i]; }
    ps += __shfl_xor(ps, 16, 64);
    ps += __shfl_xor(ps, 32, 64);
    lsum = lsum * alpha + ps;
#pragma unroll
    for (int db = 0; db < 4; ++db) accO[db] *= alpha;

    // --- P -> bf16 -> P_lds[w] rows (q=p), keys 16mb+4g+jj; zero-pad 48..63 ---
#pragma unroll
    for (int mb = 0; mb < 3; ++mb) {
      unsigned int lo = (unsigned int)f2b(pv[mb * 4 + 0]) | ((unsigned int)f2b(pv[mb * 4 + 1]) << 16);
      unsigned int hi = (unsigned int)f2b(pv[mb * 4 + 2]) | ((unsigned int)f2b(pv[mb * 4 + 3]) << 16);
      uint2 val = {lo, hi};
      *(uint2*)&P_lds[w][p * 72 + 16 * mb + 4 * g] = val;
    }
    {
      uint2 z = {0u, 0u};
      *(uint2*)&P_lds[w][p * 72 + 48 + 4 * g] = z;
    }

    // --- PV: O^T[d][q] += Vt · P^T ---
    const s16x8 pf0 = *(const s16x8*)&P_lds[w][p * 72 + g * 8];
    const s16x8 pf1 = *(const s16x8*)&P_lds[w][p * 72 + 32 + g * 8];
#pragma unroll
    for (int db = 0; db < 4; ++db) {
      const int vrow = (16 * db + p) * 48;
      s16x8 vf0 = *(const s16x8*)&Vt_lds[vrow + g * 8];
      s16x8 vf1 = *(const s16x8*)&Vt_lds[vrow + 32 + g * 8];
      accO[db] = __builtin_amdgcn_mfma_f32_16x16x32_bf16(vf0, pf0, accO[db], 0, 0, 0);
      accO[db] = __builtin_amdgcn_mfma_f32_16x16x32_bf16(vf1, pf1, accO[db], 0, 0, 0);
    }
    __syncthreads();
  }

  // epilogue: write unnormalized partial O (f32) + (m, lsum)
  const int qrow = l0 + w * 16 + p;
  float* obase = Opart + (((size_t)half * NHEAD + n) * LTOK + qrow) * HDIM;
#pragma unroll
  for (int db = 0; db < 4; ++db) {
    float4 v = {accO[db][0], accO[db][1], accO[db][2], accO[db][3]};
    *(float4*)&obase[16 * db + 4 * g] = v;
  }
  if (g == 0) {
    float* mlp = ml + (((size_t)half * NHEAD + n) * LTOK + qrow) * 2;
    mlp[0] = m;
    mlp[1] = lsum;
  }
}

// ---------------- combine split-KV partials -> bf16 attn output ----------------
// 864 blocks x 256 threads; thread = (l, n, 8-d group)
__global__ __launch_bounds__(256) void combine_kernel(const float* __restrict__ Opart,
                                                      const float* __restrict__ ml,
                                                      unsigned short* __restrict__ out) {
  const int idx = blockIdx.x * 256 + threadIdx.x;  // < L*NH*8
  const int rem = idx % 96;
  const int l = idx / 96;
  const int nn = rem >> 3, dg = rem & 7;
  const float* mlp0 = ml + (((size_t)0 * NHEAD + nn) * LTOK + l) * 2;
  const float* mlp1 = ml + (((size_t)1 * NHEAD + nn) * LTOK + l) * 2;
  const float m0 = mlp0[0], l0 = mlp0[1];
  const float m1 = mlp1[0], l1 = mlp1[1];
  const float M = fmaxf(m0, m1);
  const float w0 = __expf(m0 - M), w1 = __expf(m1 - M);
  const float inv = 1.0f / (l0 * w0 + l1 * w1);
  const float* b0 = Opart + (((size_t)0 * NHEAD + nn) * LTOK + l) * HDIM + dg * 8;
  const float* b1 = Opart + (((size_t)1 * NHEAD + nn) * LTOK + l) * HDIM + dg * 8;
  float4 a0 = *(const float4*)b0, a1 = *(const float4*)(b0 + 4);
  float4 c0 = *(const float4*)b1, c1 = *(const float4*)(b1 + 4);
  alignas(16) unsigned short o[8];
  o[0] = f2b((a0.x * w0 + c0.x * w1) * inv);
  o[1] = f2b((a0.y * w0 + c0.y * w1) * inv);
  o[2] = f2b((a0.z * w0 + c0.z * w1) * inv);
  o[3] = f2b((a0.w * w0 + c0.w * w1) * inv);
  o[4] = f2b((a1.x * w0 + c1.x * w1) * inv);
  o[5] = f2b((a1.y * w0 + c1.y * w1) * inv);
  o[6] = f2b((a1.z * w0 + c1.z * w1) * inv);
  o[7] = f2b((a1.w * w0 + c1.w * w1) * inv);
  *(uint4*)&out[(size_t)l * CDIM + nn * HDIM + dg * 8] = *(const uint4*)o;
}

// ---------------- launch ----------------
extern "C" void kernel_launch(void* const* d_in, const int* in_sizes, int n_in,
                              void* d_out, int out_size, void* d_ws, size_t ws_size,
                              hipStream_t stream) {
  const float* x     = (const float*)d_in[0];
  const float* ln1w  = (const float*)d_in[1];
  const float* ln1b  = (const float*)d_in[2];
  const float* qkvw  = (const float*)d_in[3];
  const float* qkvb  = (const float*)d_in[4];
  const float* relh  = (const float*)d_in[5];
  const float* relw  = (const float*)d_in[6];
  const float* projw = (const float*)d_in[7];
  const float* projb = (const float*)d_in[8];
  const float* ln2w  = (const float*)d_in[9];
  const float* ln2b  = (const float*)d_in[10];
  const float* fc1w  = (const float*)d_in[11];
  const float* fc1b  = (const float*)d_in[12];
  const float* fc2w  = (const float*)d_in[13];
  const float* fc2b  = (const float*)d_in[14];
  float* out = (float*)d_out;
  float* ws = (float*)d_ws;

  float* qkv = ws;                             // L*3C f32 (21.2 MB)
  float* x1  = qkv + (size_t)LTOK * 3 * CDIM;  // L*C f32 (overlaid by Qb/Kb before proj)
  float* cs  = x1 + (size_t)LTOK * CDIM;
  float* sn  = cs + (size_t)LTOK * 32;
  unsigned short* h_bf    = (unsigned short*)(sn + (size_t)LTOK * 32);
  unsigned short* attn_bf = h_bf + (size_t)LTOK * CDIM;
  unsigned short* wq      = attn_bf + (size_t)LTOK * CDIM;
  unsigned short* wproj   = wq + (size_t)3 * CDIM * CDIM;
  unsigned short* wfc1    = wproj + (size_t)CDIM * CDIM;
  unsigned short* wfc2    = wfc1 + (size_t)4 * CDIM * CDIM;
  unsigned short* Qb      = (unsigned short*)x1;   // 12*2304*64 (Qb+Kb fit x1 exactly)
  unsigned short* Kb      = Qb + (size_t)NHEAD * LTOK * HDIM;
  unsigned short* Vb      = wq;                    // overlay: wq dead after qkv GEMM
  // overlays of qkv region (dead after prep): split-KV partials, then fc1 output
  float* Opart = qkv;                              // 2*12*2304*64 f32 = 14.2 MB
  float* mlbuf = Opart + (size_t)2 * NHEAD * LTOK * HDIM;  // 2*12*2304*2 f32
  unsigned short* m1_bf = (unsigned short*)qkv;    // fc1 out (after combine consumed Opart)

  f2b_kernel<<<(3 * CDIM * CDIM / 8 + 255) / 256, 256, 0, stream>>>(qkvw, wq, 3 * CDIM * CDIM);
  f2b_kernel<<<(CDIM * CDIM / 8 + 255) / 256, 256, 0, stream>>>(projw, wproj, CDIM * CDIM);
  f2b_kernel<<<(4 * CDIM * CDIM / 8 + 255) / 256, 256, 0, stream>>>(fc1w, wfc1, 4 * CDIM * CDIM);
  f2b_kernel<<<(4 * CDIM * CDIM / 8 + 255) / 256, 256, 0, stream>>>(fc2w, wfc2, 4 * CDIM * CDIM);

  ln_kernel<<<LTOK, 256, 0, stream>>>(x, ln1w, ln1b, h_bf);
  mfma_gemm<false, false, false><<<dim3(18, 18), 256, 0, stream>>>(
      h_bf, wq, qkvb, nullptr, qkv, LTOK, 3 * CDIM, CDIM);
  rope_cs_kernel<<<288, 256, 0, stream>>>(cs, sn);
  prep_kernel<<<dim3(36, 12), 256, 0, stream>>>(qkv, cs, sn, Qb, Kb, Vb);
  attn_mfma<<<dim3(36, 12, 2), 256, 0, stream>>>(Qb, Kb, Vb, relh, relw, Opart, mlbuf);
  combine_kernel<<<864, 256, 0, stream>>>(Opart, mlbuf, attn_bf);
  mfma_gemm<false, true, false><<<dim3(6, 18), 256, 0, stream>>>(
      attn_bf, wproj, projb, x, x1, LTOK, CDIM, CDIM);
  ln_kernel<<<LTOK, 256, 0, stream>>>(x1, ln2w, ln2b, h_bf);
  mfma_gemm<true, false, true><<<dim3(24, 18), 256, 0, stream>>>(
      h_bf, wfc1, fc1b, nullptr, m1_bf, LTOK, 4 * CDIM, CDIM);
  mfma_gemm<false, true, false><<<dim3(6, 18), 256, 0, stream>>>(
      m1_bf, wfc2, fc2b, x1, out, LTOK, CDIM, 4 * CDIM);
}